// Round 1
// baseline (182.729 us; speedup 1.0000x reference)
//
#include <hip/hip_runtime.h>
#include <stdint.h>

#define HID 128

typedef __bf16 bf16x8 __attribute__((ext_vector_type(8)));
typedef float f32x4 __attribute__((ext_vector_type(4)));

// f32 -> bf16 round-to-nearest-even (inputs are finite; no NaN handling needed)
__device__ __forceinline__ unsigned short f2bf(float x) {
  unsigned int u = __float_as_uint(x);
  u += 0x7fffu + ((u >> 16) & 1u);
  return (unsigned short)(u >> 16);
}

// ---------- pass 1a: z_author f32 -> bf16 (8 elems / iter, vectorized) ----------
__global__ void cvt_z_kernel(const float* __restrict__ z,
                             unsigned short* __restrict__ zb, long n8) {
  long i = (long)blockIdx.x * blockDim.x + threadIdx.x;
  const long stride = (long)gridDim.x * blockDim.x;
  const float4* zf = (const float4*)z;
  uint4* o = (uint4*)zb;
  for (; i < n8; i += stride) {
    float4 v0 = zf[2 * i];
    float4 v1 = zf[2 * i + 1];
    uint4 w;
    w.x = f2bf(v0.x) | ((unsigned)f2bf(v0.y) << 16);
    w.y = f2bf(v0.z) | ((unsigned)f2bf(v0.w) << 16);
    w.z = f2bf(v1.x) | ((unsigned)f2bf(v1.y) << 16);
    w.w = f2bf(v1.z) | ((unsigned)f2bf(v1.w) << 16);
    o[i] = w;
  }
}

// ---------- pass 1b: W1 [256][128] f32 -> Wt[n][k] bf16, XOR-swizzled k ----------
// Wt element (n,k) stored at n*256 + (k ^ ((n&7)<<3))  -> conflict-free ds_read_b128
__global__ void cvt_w1_kernel(const float* __restrict__ W1,
                              unsigned short* __restrict__ w1t) {
  int idx = blockIdx.x * blockDim.x + threadIdx.x;
  if (idx < 256 * HID) {
    int k = idx >> 7, n = idx & 127;
    w1t[n * 256 + (k ^ ((n & 7) << 3))] = f2bf(W1[idx]);
  }
}

// ---------- main: per block 128 edges; per wave 32 edges x 128 cols via MFMA ----------
template <bool ZB>
__global__ __launch_bounds__(256, 2) void edge_mlp_kernel(
    const float* __restrict__ zf, const unsigned short* __restrict__ zb,
    const int* __restrict__ eli, const unsigned short* __restrict__ w1t,
    const float* __restrict__ b1, const float* __restrict__ W2,
    const float* __restrict__ b2, float* __restrict__ out, int nE) {
  __shared__ __align__(16) unsigned short wt[128 * 256];  // 64 KB, swizzled Wt
  const int tid = threadIdx.x;
  {  // linear, conflict-free 16B-per-lane staging of swizzled Wt
    const uint4* g = (const uint4*)w1t;
    uint4* s = (uint4*)wt;
#pragma unroll
    for (int j = 0; j < 16; ++j) s[tid + j * 256] = g[tid + j * 256];
  }
  __syncthreads();

  const int lane = tid & 63;
  const int wid = tid >> 6;
  const int l15 = lane & 15;
  const int l4 = lane >> 4;
  const int koff = l4 * 8;               // 8-contiguous-k chunk per lane group
  const int xorv = (lane & 7) << 3;      // matches the stored swizzle ((n&7)<<3)

  const int ebase = blockIdx.x * 128 + wid * 32;

  // edge ids for the two 16-row m-groups (A-frag row = lane&15)
  const int e0 = ebase + l15;
  const int e1 = ebase + 16 + l15;
  const int e0c = e0 < nE ? e0 : 0;
  const int e1c = e1 < nE ? e1 : 0;
  const int r0 = eli[e0c], c0 = eli[nE + e0c];
  const int r1 = eli[e1c], c1 = eli[nE + e1c];

  f32x4 acc[2][8] = {};  // [m-group][n-frag], fp32 accumulators

#pragma unroll
  for (int ks = 0; ks < 8; ++ks) {
    const int half = ks >> 2;                // 0: row node, 1: col node
    const int kk = (ks & 3) * 32 + koff;     // k within the 128-wide half
    bf16x8 a0, a1;
    if (ZB) {
      a0 = __builtin_bit_cast(bf16x8, *(const uint4*)(zb + (long)(half ? c0 : r0) * HID + kk));
      a1 = __builtin_bit_cast(bf16x8, *(const uint4*)(zb + (long)(half ? c1 : r1) * HID + kk));
    } else {
      const float* p0 = zf + (long)(half ? c0 : r0) * HID + kk;
      const float* p1 = zf + (long)(half ? c1 : r1) * HID + kk;
      float4 u0 = *(const float4*)p0, u1 = *(const float4*)(p0 + 4);
      float4 v0 = *(const float4*)p1, v1 = *(const float4*)(p1 + 4);
      uint4 wa, wb;
      wa.x = f2bf(u0.x) | ((unsigned)f2bf(u0.y) << 16);
      wa.y = f2bf(u0.z) | ((unsigned)f2bf(u0.w) << 16);
      wa.z = f2bf(u1.x) | ((unsigned)f2bf(u1.y) << 16);
      wa.w = f2bf(u1.z) | ((unsigned)f2bf(u1.w) << 16);
      wb.x = f2bf(v0.x) | ((unsigned)f2bf(v0.y) << 16);
      wb.y = f2bf(v0.z) | ((unsigned)f2bf(v0.w) << 16);
      wb.z = f2bf(v1.x) | ((unsigned)f2bf(v1.y) << 16);
      wb.w = f2bf(v1.z) | ((unsigned)f2bf(v1.w) << 16);
      a0 = __builtin_bit_cast(bf16x8, wa);
      a1 = __builtin_bit_cast(bf16x8, wb);
    }
    const int klog = ks * 32 + koff;
#pragma unroll
    for (int nf = 0; nf < 8; ++nf) {
      const int n = nf * 16 + l15;  // B-frag col = lane&15 (symmetric to A)
      const bf16x8 b = __builtin_bit_cast(
          bf16x8, *(const uint4*)&wt[n * 256 + (klog ^ xorv)]);
      acc[0][nf] = __builtin_amdgcn_mfma_f32_16x16x32_bf16(a0, b, acc[0][nf], 0, 0, 0);
      acc[1][nf] = __builtin_amdgcn_mfma_f32_16x16x32_bf16(a1, b, acc[1][nf], 0, 0, 0);
    }
  }

  // epilogue: bias + relu + W2 dot in fp32, then 16-lane reduce
  float b1v[8], w2v[8];
#pragma unroll
  for (int nf = 0; nf < 8; ++nf) {
    b1v[nf] = b1[nf * 16 + l15];
    w2v[nf] = W2[nf * 16 + l15];
  }
  const float bias2 = b2[0];

#pragma unroll
  for (int mg = 0; mg < 2; ++mg) {
    float p0 = 0.f, p1 = 0.f, p2 = 0.f, p3 = 0.f;
#pragma unroll
    for (int nf = 0; nf < 8; ++nf) {
      f32x4 h = acc[mg][nf];
      float t;
      t = h[0] + b1v[nf]; p0 += (t > 0.f ? t : 0.f) * w2v[nf];
      t = h[1] + b1v[nf]; p1 += (t > 0.f ? t : 0.f) * w2v[nf];
      t = h[2] + b1v[nf]; p2 += (t > 0.f ? t : 0.f) * w2v[nf];
      t = h[3] + b1v[nf]; p3 += (t > 0.f ? t : 0.f) * w2v[nf];
    }
#pragma unroll
    for (int off = 1; off < 16; off <<= 1) {
      p0 += __shfl_xor(p0, off);
      p1 += __shfl_xor(p1, off);
      p2 += __shfl_xor(p2, off);
      p3 += __shfl_xor(p3, off);
    }
    if (l15 == 0) {
      // C row = (lane>>4)*4 + reg  (HW-verified mapping)
      const int m0 = ebase + mg * 16 + l4 * 4;
      if (m0 + 0 < nE) out[m0 + 0] = p0 + bias2;
      if (m0 + 1 < nE) out[m0 + 1] = p1 + bias2;
      if (m0 + 2 < nE) out[m0 + 2] = p2 + bias2;
      if (m0 + 3 < nE) out[m0 + 3] = p3 + bias2;
    }
  }
}

// ---------- safety net if workspace is unexpectedly tiny ----------
__global__ void naive_kernel(const float* __restrict__ z, const int* __restrict__ eli,
                             const float* __restrict__ W1, const float* __restrict__ b1,
                             const float* __restrict__ W2, const float* __restrict__ b2,
                             float* __restrict__ out, int nE) {
  int e = blockIdx.x * blockDim.x + threadIdx.x;
  if (e >= nE) return;
  const float* zr = z + (long)eli[e] * HID;
  const float* zc = z + (long)eli[nE + e] * HID;
  float s = b2[0];
  for (int n = 0; n < HID; ++n) {
    float h = b1[n];
    for (int k = 0; k < HID; ++k)
      h += zr[k] * W1[k * HID + n] + zc[k] * W1[(k + HID) * HID + n];
    s += (h > 0.f ? h : 0.f) * W2[n];
  }
  out[e] = s;
}

extern "C" void kernel_launch(void* const* d_in, const int* in_sizes, int n_in,
                              void* d_out, int out_size, void* d_ws, size_t ws_size,
                              hipStream_t stream) {
  const float* z = (const float*)d_in[0];
  const int* eli = (const int*)d_in[1];
  const float* W1 = (const float*)d_in[2];
  const float* b1 = (const float*)d_in[3];
  const float* W2 = (const float*)d_in[4];
  const float* b2 = (const float*)d_in[5];
  float* out = (float*)d_out;

  const int nE = out_size;
  const long nZ = in_sizes[0];  // n_nodes * HID
  const size_t W1T_BYTES = 256 * HID * sizeof(unsigned short);  // 64 KB
  const size_t ZB_BYTES = (size_t)nZ * 2;

  if (ws_size < W1T_BYTES) {  // should never happen; stay correct regardless
    naive_kernel<<<(nE + 255) / 256, 256, 0, stream>>>(z, eli, W1, b1, W2, b2, out, nE);
    return;
  }

  unsigned short* w1t = (unsigned short*)d_ws;
  unsigned short* zb = (unsigned short*)((char*)d_ws + W1T_BYTES);
  const bool use_zb = ws_size >= W1T_BYTES + ZB_BYTES;

  cvt_w1_kernel<<<(256 * HID + 255) / 256, 256, 0, stream>>>(W1, w1t);
  if (use_zb) cvt_z_kernel<<<2048, 256, 0, stream>>>(z, zb, nZ / 8);

  const int nblocks = (nE + 127) / 128;
  if (use_zb)
    edge_mlp_kernel<true><<<nblocks, 256, 0, stream>>>(z, zb, eli, w1t, b1, W2, b2, out, nE);
  else
    edge_mlp_kernel<false><<<nblocks, 256, 0, stream>>>(z, zb, eli, w1t, b1, W2, b2, out, nE);
}

// Round 2
// 174.188 us; speedup vs baseline: 1.0490x; 1.0490x over previous
//
#include <hip/hip_runtime.h>
#include <stdint.h>

#define HID 128

typedef __bf16 bf16x8 __attribute__((ext_vector_type(8)));
typedef float f32x4 __attribute__((ext_vector_type(4)));

// f32 -> bf16 round-to-nearest-even (inputs are finite; no NaN handling needed)
__device__ __forceinline__ unsigned short f2bf(float x) {
  unsigned int u = __float_as_uint(x);
  u += 0x7fffu + ((u >> 16) & 1u);
  return (unsigned short)(u >> 16);
}

// ---------- pass 1a: z_author f32 -> bf16 (8 elems / iter, vectorized) ----------
__global__ void cvt_z_kernel(const float* __restrict__ z,
                             unsigned short* __restrict__ zb, long n8) {
  long i = (long)blockIdx.x * blockDim.x + threadIdx.x;
  const long stride = (long)gridDim.x * blockDim.x;
  const float4* zf = (const float4*)z;
  uint4* o = (uint4*)zb;
  for (; i < n8; i += stride) {
    float4 v0 = zf[2 * i];
    float4 v1 = zf[2 * i + 1];
    uint4 w;
    w.x = f2bf(v0.x) | ((unsigned)f2bf(v0.y) << 16);
    w.y = f2bf(v0.z) | ((unsigned)f2bf(v0.w) << 16);
    w.z = f2bf(v1.x) | ((unsigned)f2bf(v1.y) << 16);
    w.w = f2bf(v1.z) | ((unsigned)f2bf(v1.w) << 16);
    o[i] = w;
  }
}

// ---------- pass 1b: W1 [256][128] f32 -> Wt[n][k] bf16, XOR-swizzled k ----------
// Wt element (n,k) stored at n*256 + (k ^ ((n&7)<<3))  -> conflict-free ds_read_b128
__global__ void cvt_w1_kernel(const float* __restrict__ W1,
                              unsigned short* __restrict__ w1t) {
  int idx = blockIdx.x * blockDim.x + threadIdx.x;
  if (idx < 256 * HID) {
    int k = idx >> 7, n = idx & 127;
    w1t[n * 256 + (k ^ ((n & 7) << 3))] = f2bf(W1[idx]);
  }
}

// ---------- main: 512 thr/block, 256 edges/block; per wave 32 edges x 128 cols ----------
// 64 KB LDS @ 512 thr -> 2 blocks/CU = 16 waves/CU = 4 waves/SIMD (2x round-1 TLP)
template <bool ZB>
__global__ __launch_bounds__(512, 4) void edge_mlp_kernel(
    const float* __restrict__ zf, const unsigned short* __restrict__ zb,
    const int* __restrict__ eli, const unsigned short* __restrict__ w1t,
    const float* __restrict__ b1, const float* __restrict__ W2,
    const float* __restrict__ b2, float* __restrict__ out, int nE) {
  __shared__ __align__(16) unsigned short wt[128 * 256];  // 64 KB, swizzled Wt
  const int tid = threadIdx.x;
  {  // linear, conflict-free 16B-per-lane staging of swizzled Wt
    const uint4* g = (const uint4*)w1t;
    uint4* s = (uint4*)wt;
#pragma unroll
    for (int j = 0; j < 8; ++j) s[tid + j * 512] = g[tid + j * 512];
  }
  __syncthreads();

  const int lane = tid & 63;
  const int wid = tid >> 6;  // 0..7
  const int l15 = lane & 15;
  const int l4 = lane >> 4;
  const int koff = l4 * 8;               // 8-contiguous-k chunk per lane group
  const int xorv = (lane & 7) << 3;      // matches the stored swizzle ((n&7)<<3)

  const int ebase = blockIdx.x * 256 + wid * 32;

  // edge ids for the two 16-row m-groups (A-frag row = lane&15)
  const int e0 = ebase + l15;
  const int e1 = ebase + 16 + l15;
  const int e0c = e0 < nE ? e0 : 0;
  const int e1c = e1 < nE ? e1 : 0;
  const int r0 = eli[e0c], c0 = eli[nE + e0c];
  const int r1 = eli[e1c], c1 = eli[nE + e1c];

  f32x4 acc[2][8] = {};  // [m-group][n-frag], fp32 accumulators

#pragma unroll
  for (int ks = 0; ks < 8; ++ks) {
    const int half = ks >> 2;                // 0: row node, 1: col node
    const int kk = (ks & 3) * 32 + koff;     // k within the 128-wide half
    bf16x8 a0, a1;
    if (ZB) {
      a0 = __builtin_bit_cast(bf16x8, *(const uint4*)(zb + (long)(half ? c0 : r0) * HID + kk));
      a1 = __builtin_bit_cast(bf16x8, *(const uint4*)(zb + (long)(half ? c1 : r1) * HID + kk));
    } else {
      const float* p0 = zf + (long)(half ? c0 : r0) * HID + kk;
      const float* p1 = zf + (long)(half ? c1 : r1) * HID + kk;
      float4 u0 = *(const float4*)p0, u1 = *(const float4*)(p0 + 4);
      float4 v0 = *(const float4*)p1, v1 = *(const float4*)(p1 + 4);
      uint4 wa, wb;
      wa.x = f2bf(u0.x) | ((unsigned)f2bf(u0.y) << 16);
      wa.y = f2bf(u0.z) | ((unsigned)f2bf(u0.w) << 16);
      wa.z = f2bf(u1.x) | ((unsigned)f2bf(u1.y) << 16);
      wa.w = f2bf(u1.z) | ((unsigned)f2bf(u1.w) << 16);
      wb.x = f2bf(v0.x) | ((unsigned)f2bf(v0.y) << 16);
      wb.y = f2bf(v0.z) | ((unsigned)f2bf(v0.w) << 16);
      wb.z = f2bf(v1.x) | ((unsigned)f2bf(v1.y) << 16);
      wb.w = f2bf(v1.z) | ((unsigned)f2bf(v1.w) << 16);
      a0 = __builtin_bit_cast(bf16x8, wa);
      a1 = __builtin_bit_cast(bf16x8, wb);
    }
    const int klog = ks * 32 + koff;
#pragma unroll
    for (int nf = 0; nf < 8; ++nf) {
      const int n = nf * 16 + l15;  // B-frag col = lane&15 (symmetric to A)
      const bf16x8 b = __builtin_bit_cast(
          bf16x8, *(const uint4*)&wt[n * 256 + (klog ^ xorv)]);
      acc[0][nf] = __builtin_amdgcn_mfma_f32_16x16x32_bf16(a0, b, acc[0][nf], 0, 0, 0);
      acc[1][nf] = __builtin_amdgcn_mfma_f32_16x16x32_bf16(a1, b, acc[1][nf], 0, 0, 0);
    }
  }

  // epilogue: bias + relu + W2 dot in fp32, then 16-lane reduce
  // (loaded AFTER the MFMA loop to keep live range short under the 128-VGPR cap)
  float b1v[8], w2v[8];
#pragma unroll
  for (int nf = 0; nf < 8; ++nf) {
    b1v[nf] = b1[nf * 16 + l15];
    w2v[nf] = W2[nf * 16 + l15];
  }
  const float bias2 = b2[0];

#pragma unroll
  for (int mg = 0; mg < 2; ++mg) {
    float p0 = 0.f, p1 = 0.f, p2 = 0.f, p3 = 0.f;
#pragma unroll
    for (int nf = 0; nf < 8; ++nf) {
      f32x4 h = acc[mg][nf];
      float t;
      t = h[0] + b1v[nf]; p0 += (t > 0.f ? t : 0.f) * w2v[nf];
      t = h[1] + b1v[nf]; p1 += (t > 0.f ? t : 0.f) * w2v[nf];
      t = h[2] + b1v[nf]; p2 += (t > 0.f ? t : 0.f) * w2v[nf];
      t = h[3] + b1v[nf]; p3 += (t > 0.f ? t : 0.f) * w2v[nf];
    }
#pragma unroll
    for (int off = 1; off < 16; off <<= 1) {
      p0 += __shfl_xor(p0, off);
      p1 += __shfl_xor(p1, off);
      p2 += __shfl_xor(p2, off);
      p3 += __shfl_xor(p3, off);
    }
    if (l15 == 0) {
      // C row = (lane>>4)*4 + reg  (HW-verified mapping)
      const int m0 = ebase + mg * 16 + l4 * 4;
      if (m0 + 0 < nE) out[m0 + 0] = p0 + bias2;
      if (m0 + 1 < nE) out[m0 + 1] = p1 + bias2;
      if (m0 + 2 < nE) out[m0 + 2] = p2 + bias2;
      if (m0 + 3 < nE) out[m0 + 3] = p3 + bias2;
    }
  }
}

// ---------- safety net if workspace is unexpectedly tiny ----------
__global__ void naive_kernel(const float* __restrict__ z, const int* __restrict__ eli,
                             const float* __restrict__ W1, const float* __restrict__ b1,
                             const float* __restrict__ W2, const float* __restrict__ b2,
                             float* __restrict__ out, int nE) {
  int e = blockIdx.x * blockDim.x + threadIdx.x;
  if (e >= nE) return;
  const float* zr = z + (long)eli[e] * HID;
  const float* zc = z + (long)eli[nE + e] * HID;
  float s = b2[0];
  for (int n = 0; n < HID; ++n) {
    float h = b1[n];
    for (int k = 0; k < HID; ++k)
      h += zr[k] * W1[k * HID + n] + zc[k] * W1[(k + HID) * HID + n];
    s += (h > 0.f ? h : 0.f) * W2[n];
  }
  out[e] = s;
}

extern "C" void kernel_launch(void* const* d_in, const int* in_sizes, int n_in,
                              void* d_out, int out_size, void* d_ws, size_t ws_size,
                              hipStream_t stream) {
  const float* z = (const float*)d_in[0];
  const int* eli = (const int*)d_in[1];
  const float* W1 = (const float*)d_in[2];
  const float* b1 = (const float*)d_in[3];
  const float* W2 = (const float*)d_in[4];
  const float* b2 = (const float*)d_in[5];
  float* out = (float*)d_out;

  const int nE = out_size;
  const long nZ = in_sizes[0];  // n_nodes * HID
  const size_t W1T_BYTES = 256 * HID * sizeof(unsigned short);  // 64 KB
  const size_t ZB_BYTES = (size_t)nZ * 2;

  if (ws_size < W1T_BYTES) {  // should never happen; stay correct regardless
    naive_kernel<<<(nE + 255) / 256, 256, 0, stream>>>(z, eli, W1, b1, W2, b2, out, nE);
    return;
  }

  unsigned short* w1t = (unsigned short*)d_ws;
  unsigned short* zb = (unsigned short*)((char*)d_ws + W1T_BYTES);
  const bool use_zb = ws_size >= W1T_BYTES + ZB_BYTES;

  cvt_w1_kernel<<<(256 * HID + 255) / 256, 256, 0, stream>>>(W1, w1t);
  if (use_zb) cvt_z_kernel<<<2048, 256, 0, stream>>>(z, zb, nZ / 8);

  const int nblocks = (nE + 255) / 256;
  if (use_zb)
    edge_mlp_kernel<true><<<nblocks, 512, 0, stream>>>(z, zb, eli, w1t, b1, W2, b2, out, nE);
  else
    edge_mlp_kernel<false><<<nblocks, 512, 0, stream>>>(z, zb, eli, w1t, b1, W2, b2, out, nE);
}